// Round 1
// baseline (10915.190 us; speedup 1.0000x reference)
//
#include <hip/hip_runtime.h>

#define N_NODES 100000
#define N_EDGES 3200000
#define DDIM 256

// ---------------- zero / relu helpers ----------------
__global__ __launch_bounds__(256) void zero_f4(float4* __restrict__ p) {
    int i = blockIdx.x * 256 + threadIdx.x;
    p[i] = make_float4(0.f, 0.f, 0.f, 0.f);
}

__global__ __launch_bounds__(256) void relu_f4(float4* __restrict__ p) {
    int i = blockIdx.x * 256 + threadIdx.x;
    float4 v = p[i];
    v.x = fmaxf(v.x, 0.f);
    v.y = fmaxf(v.y, 0.f);
    v.z = fmaxf(v.z, 0.f);
    v.w = fmaxf(v.w, 0.f);
    p[i] = v;
}

// ---------------- fp32 GEMM: C[N,256] = A[N,256] @ B[256,256] ----------------
// BM=64, BN=64, BK=16; 256 threads; each thread computes a 4x4 microtile.
__global__ __launch_bounds__(256) void gemm_f32(const float* __restrict__ A,
                                                const float* __restrict__ B,
                                                float* __restrict__ C, int N) {
    __shared__ float As[16][64];  // [kk][row]
    __shared__ float Bs[16][64];  // [kk][col]

    const int tid = threadIdx.x;
    const int tr = tid / 16;   // 0..15 (row group)
    const int tc = tid % 16;   // 0..15 (col group)
    const int rowBase = blockIdx.x * 64;
    const int colBase = blockIdx.y * 64;

    float acc[4][4] = {};

    // A-tile load indices: 64 rows x 16 k -> one float4 per thread
    const int lr = tid / 4;         // row in tile 0..63
    const int lc = (tid % 4) * 4;   // k offset 0,4,8,12
    // B-tile load indices: 16 k x 64 cols -> one float4 per thread
    const int bk = tid / 16;        // 0..15
    const int bc = (tid % 16) * 4;  // 0..60

    for (int k0 = 0; k0 < 256; k0 += 16) {
        const int grow = rowBase + lr;
        float4 av = make_float4(0.f, 0.f, 0.f, 0.f);
        if (grow < N) av = *(const float4*)&A[(size_t)grow * DDIM + k0 + lc];
        As[lc + 0][lr] = av.x;
        As[lc + 1][lr] = av.y;
        As[lc + 2][lr] = av.z;
        As[lc + 3][lr] = av.w;

        float4 bv = *(const float4*)&B[(size_t)(k0 + bk) * DDIM + colBase + bc];
        *(float4*)&Bs[bk][bc] = bv;

        __syncthreads();

#pragma unroll
        for (int kk = 0; kk < 16; ++kk) {
            float4 a = *(const float4*)&As[kk][tr * 4];
            float4 b = *(const float4*)&Bs[kk][tc * 4];
            acc[0][0] += a.x * b.x; acc[0][1] += a.x * b.y; acc[0][2] += a.x * b.z; acc[0][3] += a.x * b.w;
            acc[1][0] += a.y * b.x; acc[1][1] += a.y * b.y; acc[1][2] += a.y * b.z; acc[1][3] += a.y * b.w;
            acc[2][0] += a.z * b.x; acc[2][1] += a.z * b.y; acc[2][2] += a.z * b.z; acc[2][3] += a.z * b.w;
            acc[3][0] += a.w * b.x; acc[3][1] += a.w * b.y; acc[3][2] += a.w * b.z; acc[3][3] += a.w * b.w;
        }
        __syncthreads();
    }

#pragma unroll
    for (int i = 0; i < 4; ++i) {
        const int row = rowBase + tr * 4 + i;
        if (row < N) {
            float4 v = make_float4(acc[i][0], acc[i][1], acc[i][2], acc[i][3]);
            *(float4*)&C[(size_t)row * DDIM + colBase + tc * 4] = v;
        }
    }
}

// ---------------- SpMM scatter with atomics ----------------
// 4 edges per 256-thread block; 64 lanes per edge; 4 floats per lane.
__global__ __launch_bounds__(256) void spmm_scatter(const float* __restrict__ x,
                                                    const int* __restrict__ esrc,
                                                    const int* __restrict__ edst,
                                                    const float* __restrict__ evals,
                                                    float* __restrict__ out) {
    const int e = blockIdx.x * 4 + (threadIdx.x >> 6);
    const int lane = threadIdx.x & 63;
    const int s = esrc[e];
    const int d = edst[e];
    const float v = evals[e];
    const float4 xv = *(const float4*)&x[(size_t)s * DDIM + lane * 4];
    float* op = &out[(size_t)d * DDIM + lane * 4];
    atomicAdd(op + 0, v * xv.x);
    atomicAdd(op + 1, v * xv.y);
    atomicAdd(op + 2, v * xv.z);
    atomicAdd(op + 3, v * xv.w);
}

extern "C" void kernel_launch(void* const* d_in, const int* in_sizes, int n_in,
                              void* d_out, int out_size, void* d_ws, size_t ws_size,
                              hipStream_t stream) {
    const float* inputs = (const float*)d_in[0];
    const float* weight = (const float*)d_in[1];
    const int* esrc     = (const int*)d_in[2];
    const int* edst     = (const int*)d_in[3];
    const float* evals  = (const float*)d_in[4];
    float* out = (float*)d_out;
    float* x   = (float*)d_ws;  // 100000*256 floats = 102.4 MB

    const int total_f4 = N_NODES * DDIM / 4;          // 6,400,000
    const int nblk_f4  = total_f4 / 256;              // 25,000 exact

    // 1) zero the accumulator (d_out is poisoned each call)
    zero_f4<<<nblk_f4, 256, 0, stream>>>((float4*)out);

    // 2) x = inputs @ W
    dim3 ggrid((N_NODES + 63) / 64, DDIM / 64);       // 1563 x 4
    gemm_f32<<<ggrid, 256, 0, stream>>>(inputs, weight, x, N_NODES);

    // 3) scatter-accumulate messages into out
    spmm_scatter<<<N_EDGES / 4, 256, 0, stream>>>(x, esrc, edst, evals, out);

    // 4) ReLU in place
    relu_f4<<<nblk_f4, 256, 0, stream>>>((float4*)out);
}

// Round 2
// 1382.728 us; speedup vs baseline: 7.8940x; 7.8940x over previous
//
#include <hip/hip_runtime.h>

#define N_NODES 100000
#define N_EDGES 3200000
#define DDIM 256
#define SCAN_T 1024

// ---------------- fp32 GEMM: C[N,256] = A[N,256] @ B[256,256] ----------------
__global__ __launch_bounds__(256) void gemm_f32(const float* __restrict__ A,
                                                const float* __restrict__ B,
                                                float* __restrict__ C, int N) {
    __shared__ float As[16][64];  // [kk][row]
    __shared__ float Bs[16][64];  // [kk][col]

    const int tid = threadIdx.x;
    const int tr = tid / 16;
    const int tc = tid % 16;
    const int rowBase = blockIdx.x * 64;
    const int colBase = blockIdx.y * 64;

    float acc[4][4] = {};

    const int lr = tid / 4;
    const int lc = (tid % 4) * 4;
    const int bk = tid / 16;
    const int bc = (tid % 16) * 4;

    for (int k0 = 0; k0 < 256; k0 += 16) {
        const int grow = rowBase + lr;
        float4 av = make_float4(0.f, 0.f, 0.f, 0.f);
        if (grow < N) av = *(const float4*)&A[(size_t)grow * DDIM + k0 + lc];
        As[lc + 0][lr] = av.x;
        As[lc + 1][lr] = av.y;
        As[lc + 2][lr] = av.z;
        As[lc + 3][lr] = av.w;

        float4 bv = *(const float4*)&B[(size_t)(k0 + bk) * DDIM + colBase + bc];
        *(float4*)&Bs[bk][bc] = bv;

        __syncthreads();

#pragma unroll
        for (int kk = 0; kk < 16; ++kk) {
            float4 a = *(const float4*)&As[kk][tr * 4];
            float4 b = *(const float4*)&Bs[kk][tc * 4];
            acc[0][0] += a.x * b.x; acc[0][1] += a.x * b.y; acc[0][2] += a.x * b.z; acc[0][3] += a.x * b.w;
            acc[1][0] += a.y * b.x; acc[1][1] += a.y * b.y; acc[1][2] += a.y * b.z; acc[1][3] += a.y * b.w;
            acc[2][0] += a.z * b.x; acc[2][1] += a.z * b.y; acc[2][2] += a.z * b.z; acc[2][3] += a.z * b.w;
            acc[3][0] += a.w * b.x; acc[3][1] += a.w * b.y; acc[3][2] += a.w * b.z; acc[3][3] += a.w * b.w;
        }
        __syncthreads();
    }

#pragma unroll
    for (int i = 0; i < 4; ++i) {
        const int row = rowBase + tr * 4 + i;
        if (row < N) {
            float4 v = make_float4(acc[i][0], acc[i][1], acc[i][2], acc[i][3]);
            *(float4*)&C[(size_t)row * DDIM + colBase + tc * 4] = v;
        }
    }
}

// ---------------- CSR build ----------------
__global__ __launch_bounds__(256) void zero_counts(int* __restrict__ counts) {
    int i = blockIdx.x * 256 + threadIdx.x;
    if (i < N_NODES) counts[i] = 0;
}

__global__ __launch_bounds__(256) void hist_dst(const int* __restrict__ edst,
                                                int* __restrict__ counts) {
    int e = blockIdx.x * 256 + threadIdx.x;
    if (e < N_EDGES) atomicAdd(&counts[edst[e]], 1);
}

// single-block exclusive scan of counts[N_NODES] -> off[N_NODES+1], cursor copy
__global__ __launch_bounds__(SCAN_T) void scan_counts(const int* __restrict__ counts,
                                                      int* __restrict__ off,
                                                      int* __restrict__ cursor) {
    __shared__ int part[SCAN_T];
    const int t = threadIdx.x;
    const int chunk = (N_NODES + SCAN_T - 1) / SCAN_T;  // 98
    const int lo = t * chunk;
    const int hi = min(lo + chunk, N_NODES);
    int s = 0;
    for (int i = lo; i < hi; ++i) s += counts[i];
    part[t] = s;
    __syncthreads();
    for (int d = 1; d < SCAN_T; d <<= 1) {
        int add = (t >= d) ? part[t - d] : 0;
        __syncthreads();
        part[t] += add;
        __syncthreads();
    }
    int excl = part[t] - s;  // exclusive prefix of this chunk
    int run = excl;
    for (int i = lo; i < hi; ++i) {
        off[i] = run;
        cursor[i] = run;
        run += counts[i];
    }
    if (t == SCAN_T - 1) off[N_NODES] = run;
}

__global__ __launch_bounds__(256) void bin_edges(const int* __restrict__ esrc,
                                                 const int* __restrict__ edst,
                                                 const float* __restrict__ evals,
                                                 int* __restrict__ cursor,
                                                 int* __restrict__ srcp,
                                                 float* __restrict__ valp) {
    int e = blockIdx.x * 256 + threadIdx.x;
    if (e < N_EDGES) {
        const int d = edst[e];
        const int p = atomicAdd(&cursor[d], 1);
        srcp[p] = esrc[e];
        valp[p] = evals[e];
    }
}

// ---------------- SpMM gather: one wave per destination node ----------------
__global__ __launch_bounds__(256) void spmm_gather(const float* __restrict__ x,
                                                   const int* __restrict__ off,
                                                   const int* __restrict__ srcp,
                                                   const float* __restrict__ valp,
                                                   float* __restrict__ out) {
    const int node = blockIdx.x * 4 + (threadIdx.x >> 6);
    const int lane = threadIdx.x & 63;
    if (node >= N_NODES) return;
    const int start = off[node];
    const int end = off[node + 1];

    float4 acc = make_float4(0.f, 0.f, 0.f, 0.f);

    for (int base = start; base < end; base += 64) {
        const int cnt = min(64, end - base);
        int s_l = 0;
        float v_l = 0.f;
        if (lane < cnt) {
            s_l = srcp[base + lane];
            v_l = valp[base + lane];
        }
        int j = 0;
        for (; j + 4 <= cnt; j += 4) {
            const int s0 = __shfl(s_l, j + 0);
            const int s1 = __shfl(s_l, j + 1);
            const int s2 = __shfl(s_l, j + 2);
            const int s3 = __shfl(s_l, j + 3);
            const float v0 = __shfl(v_l, j + 0);
            const float v1 = __shfl(v_l, j + 1);
            const float v2 = __shfl(v_l, j + 2);
            const float v3 = __shfl(v_l, j + 3);
            const float4 x0 = *(const float4*)&x[(size_t)s0 * DDIM + lane * 4];
            const float4 x1 = *(const float4*)&x[(size_t)s1 * DDIM + lane * 4];
            const float4 x2 = *(const float4*)&x[(size_t)s2 * DDIM + lane * 4];
            const float4 x3 = *(const float4*)&x[(size_t)s3 * DDIM + lane * 4];
            acc.x += v0 * x0.x; acc.y += v0 * x0.y; acc.z += v0 * x0.z; acc.w += v0 * x0.w;
            acc.x += v1 * x1.x; acc.y += v1 * x1.y; acc.z += v1 * x1.z; acc.w += v1 * x1.w;
            acc.x += v2 * x2.x; acc.y += v2 * x2.y; acc.z += v2 * x2.z; acc.w += v2 * x2.w;
            acc.x += v3 * x3.x; acc.y += v3 * x3.y; acc.z += v3 * x3.z; acc.w += v3 * x3.w;
        }
        for (; j < cnt; ++j) {
            const int s = __shfl(s_l, j);
            const float v = __shfl(v_l, j);
            const float4 xv = *(const float4*)&x[(size_t)s * DDIM + lane * 4];
            acc.x += v * xv.x; acc.y += v * xv.y; acc.z += v * xv.z; acc.w += v * xv.w;
        }
    }

    acc.x = fmaxf(acc.x, 0.f);
    acc.y = fmaxf(acc.y, 0.f);
    acc.z = fmaxf(acc.z, 0.f);
    acc.w = fmaxf(acc.w, 0.f);
    *(float4*)&out[(size_t)node * DDIM + lane * 4] = acc;
}

extern "C" void kernel_launch(void* const* d_in, const int* in_sizes, int n_in,
                              void* d_out, int out_size, void* d_ws, size_t ws_size,
                              hipStream_t stream) {
    const float* inputs = (const float*)d_in[0];
    const float* weight = (const float*)d_in[1];
    const int* esrc     = (const int*)d_in[2];
    const int* edst     = (const int*)d_in[3];
    const float* evals  = (const float*)d_in[4];
    float* out = (float*)d_out;

    // workspace layout
    float* x    = (float*)d_ws;                      // 25,600,000 floats
    int* counts = (int*)(x + (size_t)N_NODES * DDIM);// 100,000
    int* off    = counts + N_NODES;                  // 100,001
    int* cursor = off + N_NODES + 1;                 // 100,000
    int* srcp   = cursor + N_NODES;                  // 3,200,000
    float* valp = (float*)(srcp + N_EDGES);          // 3,200,000

    // 1) x = inputs @ W
    dim3 ggrid((N_NODES + 63) / 64, DDIM / 64);
    gemm_f32<<<ggrid, 256, 0, stream>>>(inputs, weight, x, N_NODES);

    // 2) CSR build by destination
    zero_counts<<<(N_NODES + 255) / 256, 256, 0, stream>>>(counts);
    hist_dst<<<(N_EDGES + 255) / 256, 256, 0, stream>>>(edst, counts);
    scan_counts<<<1, SCAN_T, 0, stream>>>(counts, off, cursor);
    bin_edges<<<(N_EDGES + 255) / 256, 256, 0, stream>>>(esrc, edst, evals, cursor, srcp, valp);

    // 3) gather-accumulate + fused ReLU (one wave per node)
    spmm_gather<<<N_NODES / 4, 256, 0, stream>>>(x, off, srcp, valp, out);
}

// Round 3
// 1051.307 us; speedup vs baseline: 10.3825x; 1.3152x over previous
//
#include <hip/hip_runtime.h>

#define N_NODES 100000
#define N_EDGES 3200000
#define DDIM 256
#define SCAN_T 1024

typedef short s16x8 __attribute__((ext_vector_type(8)));
typedef float f32x4 __attribute__((ext_vector_type(4)));

__device__ __forceinline__ unsigned short f32_to_bf16(float f) {
    union { float f; unsigned int u; } c; c.f = f;
    unsigned int u = c.u;
    unsigned int r = u + 0x7fffu + ((u >> 16) & 1u);  // RNE
    return (unsigned short)(r >> 16);
}
__device__ __forceinline__ float bf16_to_f32(unsigned short h) {
    union { unsigned int u; float f; } c; c.u = ((unsigned int)h) << 16;
    return c.f;
}

// ---------------- W -> Wt (bf16, transposed to [n][k]) ----------------
__global__ __launch_bounds__(256) void prep_w(const float* __restrict__ W,
                                              unsigned short* __restrict__ Wt) {
    __shared__ float tile[32][33];
    const int tx = threadIdx.x & 31;
    const int ty = threadIdx.x >> 5;  // 0..7
    const int n0 = blockIdx.x * 32;
    const int k0 = blockIdx.y * 32;
    for (int i = 0; i < 32; i += 8)
        tile[ty + i][tx] = W[(size_t)(k0 + ty + i) * DDIM + n0 + tx];
    __syncthreads();
    for (int i = 0; i < 32; i += 8)
        Wt[(size_t)(n0 + ty + i) * DDIM + k0 + tx] = f32_to_bf16(tile[tx][ty + i]);
}

// ---------------- MFMA bf16 GEMM: Xb[N,256] = bf16(A) @ bf16(W) ----------------
// Block: 256 threads = 4 waves; tile M=64, N=256 (wave w covers cols w*64..w*64+63).
// A staged to LDS (fp32->bf16) once; B-fragments read from Wt (L2-resident).
__global__ __launch_bounds__(256) void gemm_mfma(const float* __restrict__ A,
                                                 const unsigned short* __restrict__ Wt,
                                                 unsigned short* __restrict__ Xb) {
    __shared__ unsigned short As[64][DDIM + 8];  // pad +8: b128 reads hit the 8-touch/bank floor
    const int tid = threadIdx.x;
    const int rowBase = blockIdx.x * 64;

    // stage A: 16 coalesced passes of float4, convert to bf16, ushort4 LDS stores
#pragma unroll
    for (int p = 0; p < 16; ++p) {
        const int flat = p * 256 + tid;     // one float4 slot
        const int row = flat >> 6;          // 0..63
        const int k4 = (flat & 63) * 4;     // 0..252
        const int gr = rowBase + row;
        float4 v = make_float4(0.f, 0.f, 0.f, 0.f);
        if (gr < N_NODES) v = *(const float4*)&A[(size_t)gr * DDIM + k4];
        ushort4 h;
        h.x = f32_to_bf16(v.x); h.y = f32_to_bf16(v.y);
        h.z = f32_to_bf16(v.z); h.w = f32_to_bf16(v.w);
        *(ushort4*)&As[row][k4] = h;
    }
    __syncthreads();

    const int wave = tid >> 6;
    const int lane = tid & 63;
    const int lrow = lane & 15;   // m (A rows) / n (B cols) within 16x16 tile
    const int quad = lane >> 4;   // k-offset = quad*8
    const int cb = wave * 64;

    f32x4 acc[4][4] = {};

#pragma unroll
    for (int ks = 0; ks < 8; ++ks) {
        const int k0 = ks * 32 + quad * 8;
        s16x8 a[4], b[4];
#pragma unroll
        for (int ri = 0; ri < 4; ++ri)
            a[ri] = *(const s16x8*)&As[ri * 16 + lrow][k0];
#pragma unroll
        for (int ci = 0; ci < 4; ++ci)
            b[ci] = *(const s16x8*)&Wt[(size_t)(cb + ci * 16 + lrow) * DDIM + k0];
#pragma unroll
        for (int ri = 0; ri < 4; ++ri)
#pragma unroll
            for (int ci = 0; ci < 4; ++ci)
                acc[ri][ci] = __builtin_amdgcn_mfma_f32_16x16x32_bf16(a[ri], b[ci], acc[ri][ci], 0, 0, 0);
    }

    // epilogue: C/D layout col=lane&15, row=quad*4+reg
#pragma unroll
    for (int ri = 0; ri < 4; ++ri) {
        const int r0 = rowBase + ri * 16 + quad * 4;
#pragma unroll
        for (int rr = 0; rr < 4; ++rr) {
            const int row = r0 + rr;
            if (row < N_NODES) {
#pragma unroll
                for (int ci = 0; ci < 4; ++ci)
                    Xb[(size_t)row * DDIM + cb + ci * 16 + lrow] = f32_to_bf16(acc[ri][ci][rr]);
            }
        }
    }
}

// ---------------- CSR build ----------------
__global__ __launch_bounds__(256) void zero_counts(int* __restrict__ counts) {
    int i = blockIdx.x * 256 + threadIdx.x;
    if (i < N_NODES) counts[i] = 0;
}

__global__ __launch_bounds__(256) void hist_dst(const int* __restrict__ edst,
                                                int* __restrict__ counts) {
    int e = blockIdx.x * 256 + threadIdx.x;
    if (e < N_EDGES) atomicAdd(&counts[edst[e]], 1);
}

__global__ __launch_bounds__(SCAN_T) void scan_counts(const int* __restrict__ counts,
                                                      int* __restrict__ off,
                                                      int* __restrict__ cursor) {
    __shared__ int part[SCAN_T];
    const int t = threadIdx.x;
    const int chunk = (N_NODES + SCAN_T - 1) / SCAN_T;
    const int lo = t * chunk;
    const int hi = min(lo + chunk, N_NODES);
    int s = 0;
    for (int i = lo; i < hi; ++i) s += counts[i];
    part[t] = s;
    __syncthreads();
    for (int d = 1; d < SCAN_T; d <<= 1) {
        int add = (t >= d) ? part[t - d] : 0;
        __syncthreads();
        part[t] += add;
        __syncthreads();
    }
    int run = part[t] - s;
    for (int i = lo; i < hi; ++i) {
        off[i] = run;
        cursor[i] = run;
        run += counts[i];
    }
    if (t == SCAN_T - 1) off[N_NODES] = run;
}

__global__ __launch_bounds__(256) void bin_edges(const int* __restrict__ esrc,
                                                 const int* __restrict__ edst,
                                                 const float* __restrict__ evals,
                                                 int* __restrict__ cursor,
                                                 int2* __restrict__ srcval) {
    int e = blockIdx.x * 256 + threadIdx.x;
    if (e < N_EDGES) {
        const int d = edst[e];
        int2 rec;
        rec.x = esrc[e];
        rec.y = __float_as_int(evals[e]);
        srcval[atomicAdd(&cursor[d], 1)] = rec;
    }
}

// ---------------- SpMM gather (bf16 x): one wave per destination ----------------
__global__ __launch_bounds__(256) void spmm_gather(const unsigned short* __restrict__ xb,
                                                   const int* __restrict__ off,
                                                   const int2* __restrict__ srcval,
                                                   float* __restrict__ out) {
    const int node = blockIdx.x * 4 + (threadIdx.x >> 6);
    const int lane = threadIdx.x & 63;
    const int start = off[node];
    const int end = off[node + 1];

    float4 acc = make_float4(0.f, 0.f, 0.f, 0.f);

    for (int base = start; base < end; base += 64) {
        const int cnt = min(64, end - base);
        int s_l = 0;
        float v_l = 0.f;
        if (lane < cnt) {
            int2 p = srcval[base + lane];
            s_l = p.x;
            v_l = __int_as_float(p.y);
        }
        int j = 0;
        for (; j + 4 <= cnt; j += 4) {
            const int s0 = __shfl(s_l, j + 0);
            const int s1 = __shfl(s_l, j + 1);
            const int s2 = __shfl(s_l, j + 2);
            const int s3 = __shfl(s_l, j + 3);
            const float v0 = __shfl(v_l, j + 0);
            const float v1 = __shfl(v_l, j + 1);
            const float v2 = __shfl(v_l, j + 2);
            const float v3 = __shfl(v_l, j + 3);
            const ushort4 h0 = *(const ushort4*)&xb[(size_t)s0 * DDIM + lane * 4];
            const ushort4 h1 = *(const ushort4*)&xb[(size_t)s1 * DDIM + lane * 4];
            const ushort4 h2 = *(const ushort4*)&xb[(size_t)s2 * DDIM + lane * 4];
            const ushort4 h3 = *(const ushort4*)&xb[(size_t)s3 * DDIM + lane * 4];
            acc.x += v0 * bf16_to_f32(h0.x); acc.y += v0 * bf16_to_f32(h0.y);
            acc.z += v0 * bf16_to_f32(h0.z); acc.w += v0 * bf16_to_f32(h0.w);
            acc.x += v1 * bf16_to_f32(h1.x); acc.y += v1 * bf16_to_f32(h1.y);
            acc.z += v1 * bf16_to_f32(h1.z); acc.w += v1 * bf16_to_f32(h1.w);
            acc.x += v2 * bf16_to_f32(h2.x); acc.y += v2 * bf16_to_f32(h2.y);
            acc.z += v2 * bf16_to_f32(h2.z); acc.w += v2 * bf16_to_f32(h2.w);
            acc.x += v3 * bf16_to_f32(h3.x); acc.y += v3 * bf16_to_f32(h3.y);
            acc.z += v3 * bf16_to_f32(h3.z); acc.w += v3 * bf16_to_f32(h3.w);
        }
        for (; j < cnt; ++j) {
            const int s = __shfl(s_l, j);
            const float v = __shfl(v_l, j);
            const ushort4 h = *(const ushort4*)&xb[(size_t)s * DDIM + lane * 4];
            acc.x += v * bf16_to_f32(h.x); acc.y += v * bf16_to_f32(h.y);
            acc.z += v * bf16_to_f32(h.z); acc.w += v * bf16_to_f32(h.w);
        }
    }

    acc.x = fmaxf(acc.x, 0.f);
    acc.y = fmaxf(acc.y, 0.f);
    acc.z = fmaxf(acc.z, 0.f);
    acc.w = fmaxf(acc.w, 0.f);
    *(float4*)&out[(size_t)node * DDIM + lane * 4] = acc;
}

extern "C" void kernel_launch(void* const* d_in, const int* in_sizes, int n_in,
                              void* d_out, int out_size, void* d_ws, size_t ws_size,
                              hipStream_t stream) {
    const float* inputs = (const float*)d_in[0];
    const float* weight = (const float*)d_in[1];
    const int* esrc     = (const int*)d_in[2];
    const int* edst     = (const int*)d_in[3];
    const float* evals  = (const float*)d_in[4];
    float* out = (float*)d_out;

    // workspace layout (all 16B-aligned)
    unsigned short* xb = (unsigned short*)d_ws;                   // 25.6M shorts = 51.2 MB
    unsigned short* Wt = xb + (size_t)N_NODES * DDIM;             // 65536 shorts
    int* counts = (int*)(Wt + DDIM * DDIM);                       // 100000
    int* off    = counts + N_NODES;                               // 100001
    int* cursor = off + N_NODES + 1;                              // 100000
    int2* srcval = (int2*)(((uintptr_t)(cursor + N_NODES) + 15) & ~(uintptr_t)15);  // 3.2M int2

    // 1) Wt = bf16(W^T)
    prep_w<<<dim3(8, 8), 256, 0, stream>>>(weight, Wt);

    // 2) xb = bf16(inputs @ W) via MFMA
    gemm_mfma<<<(N_NODES + 63) / 64, 256, 0, stream>>>(inputs, Wt, xb);

    // 3) CSR build by destination
    zero_counts<<<(N_NODES + 255) / 256, 256, 0, stream>>>(counts);
    hist_dst<<<(N_EDGES + 255) / 256, 256, 0, stream>>>(edst, counts);
    scan_counts<<<1, SCAN_T, 0, stream>>>(counts, off, cursor);
    bin_edges<<<(N_EDGES + 255) / 256, 256, 0, stream>>>(esrc, edst, evals, cursor, srcval);

    // 4) gather-accumulate + fused ReLU (one wave per node)
    spmm_gather<<<N_NODES / 4, 256, 0, stream>>>(xb, off, srcval, out);
}

// Round 4
// 610.108 us; speedup vs baseline: 17.8906x; 1.7231x over previous
//
#include <hip/hip_runtime.h>

#define N_NODES 100000
#define N_EDGES 3200000
#define DDIM 256
#define NB 1563          // ceil(100000/64) buckets of 64 dst nodes
#define BIN_BLK 256      // blocks for hist/bin passes; 3.2M/256 = 12500 edges/block
#define CHUNK (N_EDGES / BIN_BLK)

typedef short s16x8 __attribute__((ext_vector_type(8)));
typedef float f32x4 __attribute__((ext_vector_type(4)));

__device__ __forceinline__ unsigned short f32_to_bf16(float f) {
    union { float f; unsigned int u; } c; c.f = f;
    unsigned int u = c.u;
    unsigned int r = u + 0x7fffu + ((u >> 16) & 1u);  // RNE
    return (unsigned short)(r >> 16);
}
__device__ __forceinline__ float bf16_to_f32(unsigned short h) {
    union { unsigned int u; float f; } c; c.u = ((unsigned int)h) << 16;
    return c.f;
}

// ---------------- W -> Wt (bf16, transposed to [n][k]) ----------------
__global__ __launch_bounds__(256) void prep_w(const float* __restrict__ W,
                                              unsigned short* __restrict__ Wt) {
    __shared__ float tile[32][33];
    const int tx = threadIdx.x & 31;
    const int ty = threadIdx.x >> 5;
    const int n0 = blockIdx.x * 32;
    const int k0 = blockIdx.y * 32;
    for (int i = 0; i < 32; i += 8)
        tile[ty + i][tx] = W[(size_t)(k0 + ty + i) * DDIM + n0 + tx];
    __syncthreads();
    for (int i = 0; i < 32; i += 8)
        Wt[(size_t)(n0 + ty + i) * DDIM + k0 + tx] = f32_to_bf16(tile[tx][ty + i]);
}

// ---------------- MFMA bf16 GEMM: Xb[N,256] = bf16(A) @ bf16(W) ----------------
__global__ __launch_bounds__(256) void gemm_mfma(const float* __restrict__ A,
                                                 const unsigned short* __restrict__ Wt,
                                                 unsigned short* __restrict__ Xb) {
    __shared__ unsigned short As[64][DDIM + 8];
    const int tid = threadIdx.x;
    const int rowBase = blockIdx.x * 64;

#pragma unroll
    for (int p = 0; p < 16; ++p) {
        const int flat = p * 256 + tid;
        const int row = flat >> 6;
        const int k4 = (flat & 63) * 4;
        const int gr = rowBase + row;
        float4 v = make_float4(0.f, 0.f, 0.f, 0.f);
        if (gr < N_NODES) v = *(const float4*)&A[(size_t)gr * DDIM + k4];
        ushort4 h;
        h.x = f32_to_bf16(v.x); h.y = f32_to_bf16(v.y);
        h.z = f32_to_bf16(v.z); h.w = f32_to_bf16(v.w);
        *(ushort4*)&As[row][k4] = h;
    }
    __syncthreads();

    const int wave = tid >> 6;
    const int lane = tid & 63;
    const int lrow = lane & 15;
    const int quad = lane >> 4;
    const int cb = wave * 64;

    f32x4 acc[4][4] = {};

#pragma unroll
    for (int ks = 0; ks < 8; ++ks) {
        const int k0 = ks * 32 + quad * 8;
        s16x8 a[4], b[4];
#pragma unroll
        for (int ri = 0; ri < 4; ++ri)
            a[ri] = *(const s16x8*)&As[ri * 16 + lrow][k0];
#pragma unroll
        for (int ci = 0; ci < 4; ++ci)
            b[ci] = *(const s16x8*)&Wt[(size_t)(cb + ci * 16 + lrow) * DDIM + k0];
#pragma unroll
        for (int ri = 0; ri < 4; ++ri)
#pragma unroll
            for (int ci = 0; ci < 4; ++ci)
                acc[ri][ci] = __builtin_amdgcn_mfma_f32_16x16x32_bf16(a[ri], b[ci], acc[ri][ci], 0, 0, 0);
    }

#pragma unroll
    for (int ri = 0; ri < 4; ++ri) {
        const int r0 = rowBase + ri * 16 + quad * 4;
#pragma unroll
        for (int rr = 0; rr < 4; ++rr) {
            const int row = r0 + rr;
            if (row < N_NODES) {
#pragma unroll
                for (int ci = 0; ci < 4; ++ci)
                    Xb[(size_t)row * DDIM + cb + ci * 16 + lrow] = f32_to_bf16(acc[ri][ci][rr]);
            }
        }
    }
}

// ---------------- two-level CSR build ----------------
__global__ __launch_bounds__(256) void zero_small(int* __restrict__ p, int n) {
    int i = blockIdx.x * 256 + threadIdx.x;
    if (i < n) p[i] = 0;
}

// K1: coarse histogram over NB buckets (bucket = dst>>6)
__global__ __launch_bounds__(256) void hist_coarse(const int* __restrict__ edst,
                                                   int* __restrict__ gcounts) {
    __shared__ int h[NB];
    const int tid = threadIdx.x;
    for (int i = tid; i < NB; i += 256) h[i] = 0;
    __syncthreads();
    const int lo = blockIdx.x * CHUNK;
    const int hi = lo + CHUNK;
    for (int e = lo + tid; e < hi; e += 256) atomicAdd(&h[edst[e] >> 6], 1);
    __syncthreads();
    for (int i = tid; i < NB; i += 256)
        if (h[i]) atomicAdd(&gcounts[i], h[i]);
}

// K2: scan NB bucket counts -> bbase[NB+1], bcursor copy; also off[N_NODES]=E
__global__ __launch_bounds__(256) void scan_coarse(const int* __restrict__ gcounts,
                                                   int* __restrict__ bbase,
                                                   int* __restrict__ bcursor,
                                                   int* __restrict__ off) {
    __shared__ int part[256];
    const int t = threadIdx.x;
    const int chunk = (NB + 255) / 256;  // 7
    const int lo = t * chunk;
    const int hi = min(lo + chunk, NB);
    int s = 0;
    for (int i = lo; i < hi; ++i) s += gcounts[i];
    part[t] = s;
    __syncthreads();
    for (int d = 1; d < 256; d <<= 1) {
        int a = (t >= d) ? part[t - d] : 0;
        __syncthreads();
        part[t] += a;
        __syncthreads();
    }
    int run = part[t] - s;
    for (int i = lo; i < hi; ++i) {
        bbase[i] = run;
        bcursor[i] = run;
        run += gcounts[i];
    }
    if (t == 255) {
        bbase[NB] = run;
        off[N_NODES] = run;  // == N_EDGES
    }
}

// K3: bin edges into coarse buckets. Per-block LDS hist + one span-reserve
// atomic per bucket, then scatter. Each block's per-bucket run ~8 records =
// one 64B line written by exactly one block -> full-line writebacks.
__global__ __launch_bounds__(256) void bin_coarse(const int* __restrict__ esrc,
                                                  const int* __restrict__ edst,
                                                  const float* __restrict__ evals,
                                                  int* __restrict__ bcursor,
                                                  int2* __restrict__ tmp) {
    __shared__ int h[NB];
    __shared__ int sb[NB];
    const int tid = threadIdx.x;
    for (int i = tid; i < NB; i += 256) h[i] = 0;
    __syncthreads();
    const int lo = blockIdx.x * CHUNK;
    const int hi = lo + CHUNK;
    for (int e = lo + tid; e < hi; e += 256) atomicAdd(&h[edst[e] >> 6], 1);
    __syncthreads();
    for (int i = tid; i < NB; i += 256)
        sb[i] = h[i] ? atomicAdd(&bcursor[i], h[i]) : 0;
    __syncthreads();
    for (int e = lo + tid; e < hi; e += 256) {
        const int d = edst[e];
        const int b = d >> 6;
        const int p = atomicAdd(&sb[b], 1);  // LDS atomic; sb now acts as cursor
        tmp[p] = make_int2(esrc[e] | ((d & 63) << 17), __float_as_int(evals[e]));
    }
}

// K4: refine within bucket: exact per-node CSR offsets + scatter inside a
// ~16KB window (L1/L2-resident). One workgroup per bucket.
__global__ __launch_bounds__(256) void refine(const int2* __restrict__ tmp,
                                              const int* __restrict__ bbase,
                                              int* __restrict__ off,
                                              int2* __restrict__ srcval) {
    __shared__ int nh[64];
    __shared__ int nb[64];
    const int b = blockIdx.x;
    const int tid = threadIdx.x;
    const int base = bbase[b];
    const int cnt = bbase[b + 1] - base;
    const int n0 = b * 64;
    const int nn = min(64, N_NODES - n0);
    if (tid < 64) nh[tid] = 0;
    __syncthreads();
    for (int i = tid; i < cnt; i += 256)
        atomicAdd(&nh[tmp[base + i].x >> 17], 1);
    __syncthreads();
    if (tid == 0) {
        int run = 0;
        for (int i = 0; i < 64; ++i) { nb[i] = run; run += nh[i]; }
    }
    __syncthreads();
    if (tid < nn) off[n0 + tid] = base + nb[tid];
    __syncthreads();  // off-write reads nb before pass-2 mutates it
    for (int i = tid; i < cnt; i += 256) {
        const int2 r = tmp[base + i];
        const int dl = r.x >> 17;
        const int p = atomicAdd(&nb[dl], 1);
        srcval[base + p] = make_int2(r.x & 0x1FFFF, r.y);
    }
}

// ---------------- SpMM gather (bf16 x): one wave per destination ----------------
__global__ __launch_bounds__(256) void spmm_gather(const unsigned short* __restrict__ xb,
                                                   const int* __restrict__ off,
                                                   const int2* __restrict__ srcval,
                                                   float* __restrict__ out) {
    const int node = blockIdx.x * 4 + (threadIdx.x >> 6);
    const int lane = threadIdx.x & 63;
    const int start = off[node];
    const int end = off[node + 1];

    float4 acc = make_float4(0.f, 0.f, 0.f, 0.f);

    for (int base = start; base < end; base += 64) {
        const int cnt = min(64, end - base);
        int s_l = 0;
        float v_l = 0.f;
        if (lane < cnt) {
            int2 p = srcval[base + lane];
            s_l = p.x;
            v_l = __int_as_float(p.y);
        }
        int j = 0;
        for (; j + 4 <= cnt; j += 4) {
            const int s0 = __shfl(s_l, j + 0);
            const int s1 = __shfl(s_l, j + 1);
            const int s2 = __shfl(s_l, j + 2);
            const int s3 = __shfl(s_l, j + 3);
            const float v0 = __shfl(v_l, j + 0);
            const float v1 = __shfl(v_l, j + 1);
            const float v2 = __shfl(v_l, j + 2);
            const float v3 = __shfl(v_l, j + 3);
            const ushort4 h0 = *(const ushort4*)&xb[(size_t)s0 * DDIM + lane * 4];
            const ushort4 h1 = *(const ushort4*)&xb[(size_t)s1 * DDIM + lane * 4];
            const ushort4 h2 = *(const ushort4*)&xb[(size_t)s2 * DDIM + lane * 4];
            const ushort4 h3 = *(const ushort4*)&xb[(size_t)s3 * DDIM + lane * 4];
            acc.x += v0 * bf16_to_f32(h0.x); acc.y += v0 * bf16_to_f32(h0.y);
            acc.z += v0 * bf16_to_f32(h0.z); acc.w += v0 * bf16_to_f32(h0.w);
            acc.x += v1 * bf16_to_f32(h1.x); acc.y += v1 * bf16_to_f32(h1.y);
            acc.z += v1 * bf16_to_f32(h1.z); acc.w += v1 * bf16_to_f32(h1.w);
            acc.x += v2 * bf16_to_f32(h2.x); acc.y += v2 * bf16_to_f32(h2.y);
            acc.z += v2 * bf16_to_f32(h2.z); acc.w += v2 * bf16_to_f32(h2.w);
            acc.x += v3 * bf16_to_f32(h3.x); acc.y += v3 * bf16_to_f32(h3.y);
            acc.z += v3 * bf16_to_f32(h3.z); acc.w += v3 * bf16_to_f32(h3.w);
        }
        for (; j < cnt; ++j) {
            const int s = __shfl(s_l, j);
            const float v = __shfl(v_l, j);
            const ushort4 h = *(const ushort4*)&xb[(size_t)s * DDIM + lane * 4];
            acc.x += v * bf16_to_f32(h.x); acc.y += v * bf16_to_f32(h.y);
            acc.z += v * bf16_to_f32(h.z); acc.w += v * bf16_to_f32(h.w);
        }
    }

    acc.x = fmaxf(acc.x, 0.f);
    acc.y = fmaxf(acc.y, 0.f);
    acc.z = fmaxf(acc.z, 0.f);
    acc.w = fmaxf(acc.w, 0.f);
    *(float4*)&out[(size_t)node * DDIM + lane * 4] = acc;
}

extern "C" void kernel_launch(void* const* d_in, const int* in_sizes, int n_in,
                              void* d_out, int out_size, void* d_ws, size_t ws_size,
                              hipStream_t stream) {
    const float* inputs = (const float*)d_in[0];
    const float* weight = (const float*)d_in[1];
    const int* esrc     = (const int*)d_in[2];
    const int* edst     = (const int*)d_in[3];
    const float* evals  = (const float*)d_in[4];
    float* out = (float*)d_out;

    // workspace layout (16B alignment maintained)
    unsigned short* xb = (unsigned short*)d_ws;                  // 25.6M ushort
    unsigned short* Wt = xb + (size_t)N_NODES * DDIM;            // 65536 ushort
    int* off     = (int*)(Wt + DDIM * DDIM);                     // 100001
    int* gcounts = off + N_NODES + 1;                            // NB
    int* bbase   = gcounts + NB;                                 // NB+1
    int* bcursor = bbase + NB + 1;                               // NB
    uintptr_t a  = ((uintptr_t)(bcursor + NB) + 15) & ~(uintptr_t)15;
    int2* tmp    = (int2*)a;                                     // 3.2M int2
    int2* srcval = tmp + N_EDGES;                                // 3.2M int2

    // 1) Wt = bf16(W^T)
    prep_w<<<dim3(8, 8), 256, 0, stream>>>(weight, Wt);

    // 2) xb = bf16(inputs @ W) via MFMA
    gemm_mfma<<<(N_NODES + 63) / 64, 256, 0, stream>>>(inputs, Wt, xb);

    // 3) two-level CSR build
    zero_small<<<(NB + 255) / 256, 256, 0, stream>>>(gcounts, NB);
    hist_coarse<<<BIN_BLK, 256, 0, stream>>>(edst, gcounts);
    scan_coarse<<<1, 256, 0, stream>>>(gcounts, bbase, bcursor, off);
    bin_coarse<<<BIN_BLK, 256, 0, stream>>>(esrc, edst, evals, bcursor, tmp);
    refine<<<NB, 256, 0, stream>>>(tmp, bbase, off, srcval);

    // 4) gather-accumulate + fused ReLU (one wave per node)
    spmm_gather<<<N_NODES / 4, 256, 0, stream>>>(xb, off, srcval, out);
}